// Round 3
// baseline (16964.758 us; speedup 1.0000x reference)
//
#include <hip/hip_runtime.h>

typedef unsigned short u16;
typedef unsigned int   u32;
typedef __bf16 bf16x8 __attribute__((ext_vector_type(8)));
typedef float  f32x4  __attribute__((ext_vector_type(4)));

#define NB 128   // batch
#define NH 512   // hidden
#define NA 128   // attention dim
#define NT 256   // encoder time
#define NC 256   // classes
#define NL 300   // decode steps

// ---------------- workspace layout (bytes) ----------------
static constexpr size_t OFF_BAR   = 0;                         // 4 KiB barrier area
static constexpr size_t OFF_H1    = 4096;                      // 2*128*512*2
static constexpr size_t OFF_H2    = OFF_H1   + 262144;
static constexpr size_t OFF_H3    = OFF_H2   + 262144;
static constexpr size_t OFF_C     = OFF_H3   + 262144;         // 3*128*512*4
static constexpr size_t OFF_CTX   = OFF_C    + 786432;         // 128*128*2
static constexpr size_t OFF_Q     = OFF_CTX  + 32768;          // 128*128*4
static constexpr size_t OFF_MP    = OFF_Q    + 65536;          // 128*512*4
static constexpr size_t OFF_M     = OFF_MP   + 262144;         // 128*512*2
static constexpr size_t OFF_LOG   = OFF_M    + 131072;         // 128*256*4
static constexpr size_t OFF_W1C   = OFF_LOG  + 131072;         // 2048*128*2
static constexpr size_t OFF_WHH1  = OFF_W1C  + 524288;         // 2048*512*2
static constexpr size_t OFF_WIH2  = OFF_WHH1 + 2097152;
static constexpr size_t OFF_WHH2  = OFF_WIH2 + 2097152;
static constexpr size_t OFF_WIH3  = OFF_WHH2 + 2097152;
static constexpr size_t OFF_WHH3  = OFF_WIH3 + 2097152;
static constexpr size_t OFF_WMH   = OFF_WHH3 + 2097152;        // 512*512*2
static constexpr size_t OFF_WMC   = OFF_WMH  + 524288;         // 512*128*2
static constexpr size_t OFF_WQ    = OFF_WMC  + 131072;         // 128*512*2
static constexpr size_t OFF_EMB   = OFF_WQ   + 131072;         // 256*512*2
static constexpr size_t OFF_PROJ1 = OFF_EMB  + 262144;         // 256*2048*2
static constexpr size_t OFF_BS2   = OFF_PROJ1+ 1048576;        // 2048*4
static constexpr size_t OFF_BS3   = OFF_BS2  + 8192;
static constexpr size_t OFF_KEY   = OFF_BS3  + 8192;           // 128*128*256*2
static constexpr size_t OFF_VAL   = OFF_KEY  + 8388608;
static constexpr size_t OFF_END   = OFF_VAL  + 8388608;

// ---------------- scalar helpers ----------------
__device__ __forceinline__ u16 f2bf(float f) {
  u32 u = __builtin_bit_cast(u32, f);
  u32 r = (u + 0x7FFFu + ((u >> 16) & 1u)) >> 16;
  return (u16)r;
}
__device__ __forceinline__ float bf2f(u16 h) {
  return __builtin_bit_cast(float, ((u32)h) << 16);
}
__device__ __forceinline__ float sigm(float x) { return 1.f / (1.f + __expf(-x)); }
__device__ __forceinline__ float ftanh(float x) {
  x = fminf(fmaxf(x, -15.f), 15.f);
  float e = __expf(2.f * x);
  return (e - 1.f) / (e + 1.f);
}

// ---------------- coherent (cross-XCD) access helpers ----------------
// sc0 sc1 => bypass L0/L1 and L2: reads/writes go to the device coherence point.
__device__ __forceinline__ float ld_coh_f32(const float* p) {
  float v;
  asm volatile("global_load_dword %0, %1, off sc0 sc1\n\ts_waitcnt vmcnt(0)"
               : "=v"(v) : "v"(p) : "memory");
  return v;
}
__device__ __forceinline__ u32 ld_coh_u32(const u32* p) {
  u32 v;
  asm volatile("global_load_dword %0, %1, off sc0 sc1\n\ts_waitcnt vmcnt(0)"
               : "=v"(v) : "v"(p) : "memory");
  return v;
}
__device__ __forceinline__ f32x4 ld_coh16(const u16* p) {
  f32x4 v;
  asm volatile("global_load_dwordx4 %0, %1, off sc0 sc1\n\ts_waitcnt vmcnt(0)"
               : "=v"(v) : "v"(p) : "memory");
  return v;
}
__device__ __forceinline__ void ld_coh64(const u16* p, f32x4& a, f32x4& b, f32x4& c, f32x4& d) {
  asm volatile(
      "global_load_dwordx4 %0, %4, off sc0 sc1\n\t"
      "global_load_dwordx4 %1, %4, off offset:16 sc0 sc1\n\t"
      "global_load_dwordx4 %2, %4, off offset:32 sc0 sc1\n\t"
      "global_load_dwordx4 %3, %4, off offset:48 sc0 sc1\n\t"
      "s_waitcnt vmcnt(0)"
      : "=&v"(a), "=&v"(b), "=&v"(c), "=&v"(d)
      : "v"(p) : "memory");
}
__device__ __forceinline__ void st_coh_f32(float* p, float v) {
  asm volatile("global_store_dword %0, %1, off sc0 sc1" :: "v"(p), "v"(v) : "memory");
}
__device__ __forceinline__ void st_coh_bf16(u16* p, u16 v) {
  u32 vv = v;
  asm volatile("global_store_short %0, %1, off sc0 sc1" :: "v"(p), "v"(vv) : "memory");
}

// ---------------- grid barrier (hierarchical, monotonic) ----------------
__device__ __forceinline__ void gbar(char* ws, int xcd, u32& phase) {
  // every thread drains its own coherent stores first
  asm volatile("s_waitcnt vmcnt(0)" ::: "memory");
  __syncthreads();
  if (threadIdx.x == 0) {
    u32* cx = (u32*)(ws + OFF_BAR + 256 * (size_t)(1 + xcd));
    u32* cr = (u32*)(ws + OFF_BAR);
    ++phase;
    u32 prev = __hip_atomic_fetch_add(cx, 1u, __ATOMIC_RELAXED, __HIP_MEMORY_SCOPE_AGENT);
    if (prev == phase * 32u - 1u)  // last WG of this XCD this phase
      __hip_atomic_fetch_add(cr, 1u, __ATOMIC_RELAXED, __HIP_MEMORY_SCOPE_AGENT);
    u32 tgt = phase * 8u;
    while (ld_coh_u32(cr) < tgt) __builtin_amdgcn_s_sleep(2);
  }
  __syncthreads();
}

// ---------------- workgroup reductions ----------------
__device__ __forceinline__ float wgmax(float v, float* s) {
#pragma unroll
  for (int o = 32; o; o >>= 1) v = fmaxf(v, __shfl_xor(v, o, 64));
  if ((threadIdx.x & 63) == 0) s[threadIdx.x >> 6] = v;
  __syncthreads();
  v = fmaxf(fmaxf(s[0], s[1]), fmaxf(s[2], s[3]));
  __syncthreads();
  return v;
}
__device__ __forceinline__ float wgsum(float v, float* s) {
#pragma unroll
  for (int o = 32; o; o >>= 1) v += __shfl_xor(v, o, 64);
  if ((threadIdx.x & 63) == 0) s[threadIdx.x >> 6] = v;
  __syncthreads();
  v = s[0] + s[1] + s[2] + s[3];
  __syncthreads();
  return v;
}

// ---------------- LDS staging (coherent global -> LDS) ----------------
// 16 rows x 512 bf16 (row stride 512 in global), each thread 64B contiguous
__device__ __forceinline__ void stage512(u16* sA, int lstride, int lcol0, const u16* src, int mt) {
  const int row = threadIdx.x >> 4;
  const int c4  = (threadIdx.x & 15) * 32;  // elems
  const u16* p = src + (((size_t)(mt * 16 + row)) << 9) + c4;
  f32x4 a, b, c, d;
  ld_coh64(p, a, b, c, d);
  f32x4* dst = (f32x4*)(sA + (size_t)row * lstride + lcol0 + c4);
  dst[0] = a; dst[1] = b; dst[2] = c; dst[3] = d;
}
// 16 rows x 128 bf16 (row stride 128 in global), each thread 16B
__device__ __forceinline__ void stage128(u16* sA, int lstride, int lcol0, const u16* src, int mt) {
  const int row = threadIdx.x >> 4;
  const int c1  = (threadIdx.x & 15) * 8;
  const u16* p = src + (size_t)(mt * 16 + row) * 128 + c1;
  f32x4 a = ld_coh16(p);
  *(f32x4*)(sA + (size_t)row * lstride + lcol0 + c1) = a;
}

// ---------------- MFMA tile helper ----------------
// D[b][g] += sum_k A[b][k] * W[g][k]; A staged in LDS rows, W row-major [*, kw] bf16
template <int NKS>
__device__ __forceinline__ f32x4 mm_part(f32x4 acc, const u16* sAp, int lstride, int lcol0,
                                         int ks0, const u16* W, int kw, int colbase, int lane) {
  const int ra = lane & 15, kg = lane >> 4;
  const u16* ap = sAp + (size_t)ra * lstride + lcol0 + kg * 8 + ks0 * 32;
  const u16* wp = W + (size_t)(colbase + ra) * kw + kg * 8 + (size_t)ks0 * 32;
#pragma unroll
  for (int k = 0; k < NKS; ++k) {
    bf16x8 av = *(const bf16x8*)(ap + k * 32);
    bf16x8 bv = *(const bf16x8*)(wp + k * 32);
    acc = __builtin_amdgcn_mfma_f32_16x16x32_bf16(av, bv, acc, 0, 0, 0);
  }
  return acc;
}
__device__ __forceinline__ void gx_write(float (*gx)[16][17], int wv, int lane, f32x4 acc) {
  const int col = lane & 15, r0 = (lane >> 4) * 4;
#pragma unroll
  for (int r = 0; r < 4; ++r) gx[wv][r0 + r][col] = acc[r];
}
__device__ __forceinline__ float gx_sum(float (*gx)[16][17], int bl, int jl) {
  return gx[0][bl][jl] + gx[1][bl][jl] + gx[2][bl][jl] + gx[3][bl][jl];
}

// ---------------- LSTM cell epilogue ----------------
__device__ __forceinline__ void cell_update(int layer, int mt, int ut, int t,
                                            float (*gx)[16][17], const int* Yin,
                                            const u16* proj1, const float* bsum,
                                            float* CB, u16* hout) {
  const int bl = threadIdx.x >> 4, ul = threadIdx.x & 15;
  const int bg = mt * 16 + bl, ug = ut * 16 + ul;
  float iv = gx[0][bl][ul], fv = gx[1][bl][ul], gv = gx[2][bl][ul], ov = gx[3][bl][ul];
  if (proj1) {
    const int y = Yin[bg * NL + t];
    const u16* pr = proj1 + (size_t)y * 2048 + ug;
    iv += bf2f(pr[0]); fv += bf2f(pr[512]); gv += bf2f(pr[1024]); ov += bf2f(pr[1536]);
  } else {
    iv += bsum[ug]; fv += bsum[512 + ug]; gv += bsum[1024 + ug]; ov += bsum[1536 + ug];
  }
  float* cp = CB + ((size_t)layer * NB + bg) * NH + ug;
  const float c0 = *cp;
  const float ii = sigm(iv), ff = sigm(fv), gg = ftanh(gv), oo = sigm(ov);
  const float cn = ff * c0 + ii * gg;
  *cp = cn;
  st_coh_bf16(hout + (size_t)bg * NH + ug, f2bf(oo * ftanh(cn)));
}

// ---------------- output-head pieces ----------------
// m = leaky(mp + ctx @ Wmlp_ctx.T); ctx is staged at sA cols [0,128), stride 648
__device__ __forceinline__ void mfin(int mt, int ut, const u16* sAc,
                                     const float* MP, const u16* WMC, u16* MB) {
  const int tid = threadIdx.x;
  const int jl = tid >> 4, bl = tid & 15;
  const int bg = mt * 16 + bl, j = ut * 16 + jl;
  float s = ld_coh_f32(MP + (size_t)bg * NH + j);
  const u16* wr = WMC + (size_t)j * NA;
  const u16* cr = sAc + (size_t)bl * 648;
#pragma unroll 8
  for (int k = 0; k < NA; ++k) s += bf2f(cr[k]) * bf2f(wr[k]);
  s = (s >= 0.f) ? s : 0.01f * s;
  st_coh_bf16(MB + (size_t)bg * NH + j, f2bf(s));
}

__device__ void attn_finish(int b, const float* QB, const int* flens,
                            const u16* KEY, const u16* VAL, u16* CTX, float* aux) {
  const int tid = threadIdx.x;
  if (tid < NA) aux[tid] = ld_coh_f32(QB + (size_t)b * NA + tid);
  __syncthreads();
  const int fl = flens[b] >> 3;  // frame_lens // 8
  float e = -3.0e38f;
  if (tid < fl) {
    e = 0.f;
    const u16* kp = KEY + (size_t)b * NA * NT + tid;
#pragma unroll 8
    for (int a = 0; a < NA; ++a) e += aux[a] * bf2f(kp[(size_t)a * NT]);
  }
  const float mx = wgmax(e, aux + 520);
  float ex = (tid < fl) ? __expf(e - mx) : 0.f;
  const float sm = wgsum(ex, aux + 520);
  aux[256 + tid] = ex / sm;
  __syncthreads();
  if (tid < NA) {
    float c = 0.f;
    const u16* vp = VAL + (size_t)b * NT * NA + tid;
#pragma unroll 8
    for (int t2 = 0; t2 < NT; ++t2) c += aux[256 + t2] * bf2f(vp[(size_t)t2 * NA]);
    st_coh_bf16(CTX + (size_t)b * NA + tid, f2bf(c));
  }
}

__device__ void lsm(int b, int tp, const float* LG, float* out, float* aux) {
  const int tid = threadIdx.x;
  const float l = ld_coh_f32(LG + (size_t)b * NC + tid);
  const float mx = wgmax(l, aux + 520);
  const float ex = __expf(l - mx);
  const float sm = wgsum(ex, aux + 520);
  out[((size_t)b * NL + tp) * NC + tid] = l - mx - __logf(sm);
}

// ---------------- prep kernels ----------------
__global__ void k_conv(const float* __restrict__ src, u16* __restrict__ dst,
                       int rows, int cols, int sstride, int soff) {
  const int n = rows * cols;
  for (int i = blockIdx.x * blockDim.x + threadIdx.x; i < n; i += gridDim.x * blockDim.x) {
    const int r = i / cols, c = i - r * cols;
    dst[i] = f2bf(src[(size_t)r * sstride + soff + c]);
  }
}

__global__ void k_proj1(const float* __restrict__ emb, const float* __restrict__ Wih1,
                        const float* __restrict__ bih1, const float* __restrict__ bhh1,
                        u16* __restrict__ proj) {
  __shared__ float se[8][512];
  const int c0 = (blockIdx.x >> 3) * 8;
  const int g = (blockIdx.x & 7) * 256 + threadIdx.x;
  for (int i = threadIdx.x; i < 4096; i += 256)
    se[i >> 9][i & 511] = emb[(size_t)(c0 + (i >> 9)) * NH + (i & 511)];
  __syncthreads();
  const float bb = bih1[g] + bhh1[g];
  const float* w = Wih1 + (size_t)g * 640;  // cols [0,512) multiply emb
  for (int cc = 0; cc < 8; ++cc) {
    float s = 0.f;
#pragma unroll 8
    for (int k = 0; k < 512; ++k) s += se[cc][k] * w[k];
    proj[(size_t)(c0 + cc) * 2048 + g] = f2bf(s + bb);
  }
}

__global__ void k_init(const float* h00, const float* h01, const float* h02,
                       const float* c00, const float* c01, const float* c02,
                       const float* bih2, const float* bhh2,
                       const float* bih3, const float* bhh3, char* ws) {
  const int i = blockIdx.x * 256 + threadIdx.x;  // grid 256 -> 65536 threads
  u16* H1 = (u16*)(ws + OFF_H1);
  u16* H2 = (u16*)(ws + OFF_H2);
  u16* H3 = (u16*)(ws + OFF_H3);
  float* CB = (float*)(ws + OFF_C);
  const int k = i & 511;
  H1[i] = f2bf(h00[k]); H2[i] = f2bf(h01[k]); H3[i] = f2bf(h02[k]);
  CB[i] = c00[k]; CB[65536 + i] = c01[k]; CB[131072 + i] = c02[k];
  if (i < 2048) {
    ((float*)(ws + OFF_BS2))[i] = bih2[i] + bhh2[i];
    ((float*)(ws + OFF_BS3))[i] = bih3[i] + bhh3[i];
  }
  if (i < 1024) ((u32*)(ws + OFF_BAR))[i] = 0;
}

// ---------------- the persistent decoder ----------------
__global__ void __launch_bounds__(256, 1) k_dec(
    const int* __restrict__ Yin, const int* __restrict__ flens,
    const float* __restrict__ bq, const float* __restrict__ bmlp,
    const float* __restrict__ bproj, float* __restrict__ out, char* __restrict__ ws) {
  __shared__ __align__(16) u16 sA[16 * 1040];   // 33,280 B staging
  __shared__ float gx[4][16][17];               // cross-wave exchange
  __shared__ float aux[576];

  u16* H1 = (u16*)(ws + OFF_H1);
  u16* H2 = (u16*)(ws + OFF_H2);
  u16* H3 = (u16*)(ws + OFF_H3);
  float* CB = (float*)(ws + OFF_C);
  u16* CTX = (u16*)(ws + OFF_CTX);
  float* QB = (float*)(ws + OFF_Q);
  float* MP = (float*)(ws + OFF_MP);
  u16* MB = (u16*)(ws + OFF_M);
  float* LG = (float*)(ws + OFF_LOG);
  const u16* W1C  = (const u16*)(ws + OFF_W1C);
  const u16* WHH1 = (const u16*)(ws + OFF_WHH1);
  const u16* WIH2 = (const u16*)(ws + OFF_WIH2);
  const u16* WHH2 = (const u16*)(ws + OFF_WHH2);
  const u16* WIH3 = (const u16*)(ws + OFF_WIH3);
  const u16* WHH3 = (const u16*)(ws + OFF_WHH3);
  const u16* WMH  = (const u16*)(ws + OFF_WMH);
  const u16* WMC  = (const u16*)(ws + OFF_WMC);
  const u16* WQB  = (const u16*)(ws + OFF_WQ);
  const u16* EMBB = (const u16*)(ws + OFF_EMB);
  const u16* PJ1  = (const u16*)(ws + OFF_PROJ1);
  const float* BS2 = (const float*)(ws + OFF_BS2);
  const float* BS3 = (const float*)(ws + OFF_BS3);
  const u16* KEY = (const u16*)(ws + OFF_KEY);
  const u16* VAL = (const u16*)(ws + OFF_VAL);

  const int wg = blockIdx.x, tid = threadIdx.x;
  const int lane = tid & 63, wv = tid >> 6;
  const int xcd = wg & 7, slot = wg >> 3;
  // same-ut WGs (8 batch tiles sharing a weight slice) land on one XCD
  const int ut = xcd * 4 + (slot >> 3);  // 0..31 (u-tile of 16 hidden units)
  const int mt = slot & 7;               // 0..7  (batch tile of 16)
  u32 phase = 0;

  // ======== pre-loop: q from initial h3 ========
  {
    stage512(sA, 520, 0, H3, mt);
    __syncthreads();
    if (ut < 8) {
      f32x4 acc = {0.f, 0.f, 0.f, 0.f};
      acc = mm_part<4>(acc, sA, 520, 0, wv * 4, WQB, 512, ut * 16, lane);
      gx_write(gx, wv, lane, acc);
    }
    __syncthreads();
    if (ut < 8) {
      const int bl = tid >> 4, jl = tid & 15;
      st_coh_f32(QB + (size_t)(mt * 16 + bl) * NA + ut * 16 + jl,
                 gx_sum(gx, bl, jl) + bq[ut * 16 + jl]);
    }
  }
  gbar(ws, xcd, phase);
  if (wg < NB) attn_finish(wg, QB, flens, KEY, VAL, CTX, aux);
  gbar(ws, xcd, phase);

  // ======== main loop ========
  for (int t = 0; t < NL; ++t) {
    const int o = t & 1, n = o ^ 1;
    u16* h1o = H1 + o * 65536; u16* h1n = H1 + n * 65536;
    u16* h2o = H2 + o * 65536; u16* h2n = H2 + n * 65536;
    u16* h3o = H3 + o * 65536; u16* h3n = H3 + n * 65536;

    // ---- phase A: LSTM1 (+ finish output-head m of t-1)
    {
      stage128(sA, 648, 0, CTX, mt);
      stage512(sA, 648, 128, h1o, mt);
      __syncthreads();
      f32x4 acc = {0.f, 0.f, 0.f, 0.f};
      const int colbase = wv * 512 + ut * 16;
      acc = mm_part<4>(acc, sA, 648, 0, 0, W1C, 128, colbase, lane);
      acc = mm_part<16>(acc, sA, 648, 128, 0, WHH1, 512, colbase, lane);
      gx_write(gx, wv, lane, acc);
      __syncthreads();
      cell_update(0, mt, ut, t, gx, Yin, PJ1, nullptr, CB, h1n);
      if (t >= 1) mfin(mt, ut, sA, MP, WMC, MB);
    }
    gbar(ws, xcd, phase);

    // ---- phase B: LSTM2
    {
      stage512(sA, 1032, 0, h1n, mt);
      stage512(sA, 1032, 512, h2o, mt);
      __syncthreads();
      f32x4 acc = {0.f, 0.f, 0.f, 0.f};
      const int colbase = wv * 512 + ut * 16;
      acc = mm_part<16>(acc, sA, 1032, 0, 0, WIH2, 512, colbase, lane);
      acc = mm_part<16>(acc, sA, 1032, 512, 0, WHH2, 512, colbase, lane);
      gx_write(gx, wv, lane, acc);
      __syncthreads();
      cell_update(1, mt, ut, t, gx, Yin, nullptr, BS2, CB, h2n);
    }
    gbar(ws, xcd, phase);

    // ---- phase C: LSTM3
    {
      stage512(sA, 1032, 0, h2n, mt);
      stage512(sA, 1032, 512, h3o, mt);
      __syncthreads();
      f32x4 acc = {0.f, 0.f, 0.f, 0.f};
      const int colbase = wv * 512 + ut * 16;
      acc = mm_part<16>(acc, sA, 1032, 0, 0, WIH3, 512, colbase, lane);
      acc = mm_part<16>(acc, sA, 1032, 512, 0, WHH3, 512, colbase, lane);
      gx_write(gx, wv, lane, acc);
      __syncthreads();
      cell_update(2, mt, ut, t, gx, Yin, nullptr, BS3, CB, h3n);
    }
    gbar(ws, xcd, phase);

    // ---- phase D: q(t), m_partial(t), proj(t-1)
    {
      stage512(sA, 520, 0, h3n, mt);
      const bool dop = (ut >= 16) && (t >= 1);
      if (dop) stage512(sA + 16 * 520, 520, 0, MB, mt);
      __syncthreads();
      {  // m_partial = h3 @ Wmlp_h.T + bmlp   (K split across waves)
        f32x4 acc = {0.f, 0.f, 0.f, 0.f};
        acc = mm_part<4>(acc, sA, 520, 0, wv * 4, WMH, 512, ut * 16, lane);
        gx_write(gx, wv, lane, acc);
        __syncthreads();
        const int bl = tid >> 4, jl = tid & 15;
        st_coh_f32(MP + (size_t)(mt * 16 + bl) * NH + ut * 16 + jl,
                   gx_sum(gx, bl, jl) + bmlp[ut * 16 + jl]);
        __syncthreads();
      }
      if (ut < 8) {  // q = h3 @ Wq.T + bq
        f32x4 acc = {0.f, 0.f, 0.f, 0.f};
        acc = mm_part<4>(acc, sA, 520, 0, wv * 4, WQB, 512, ut * 16, lane);
        gx_write(gx, wv, lane, acc);
        __syncthreads();
        const int bl = tid >> 4, jl = tid & 15;
        st_coh_f32(QB + (size_t)(mt * 16 + bl) * NA + ut * 16 + jl,
                   gx_sum(gx, bl, jl) + bq[ut * 16 + jl]);
      }
      if (dop) {  // logits(t-1) = m @ emb.T + bproj
        f32x4 acc = {0.f, 0.f, 0.f, 0.f};
        acc = mm_part<4>(acc, sA + 16 * 520, 520, 0, wv * 4, EMBB, 512, (ut - 16) * 16, lane);
        gx_write(gx, wv, lane, acc);
        __syncthreads();
        const int bl = tid >> 4, jl = tid & 15;
        st_coh_f32(LG + (size_t)(mt * 16 + bl) * NC + (ut - 16) * 16 + jl,
                   gx_sum(gx, bl, jl) + bproj[(ut - 16) * 16 + jl]);
      }
    }
    gbar(ws, xcd, phase);

    // ---- phase E: attention finish (ctx(t)) + log_softmax(t-1)
    if (wg < NB)          attn_finish(wg, QB, flens, KEY, VAL, CTX, aux);
    else if (t >= 1)      lsm(wg - NB, t - 1, LG, out, aux);
    gbar(ws, xcd, phase);
  }

  // ======== tail: finish output head of t = 299 ========
  {
    stage128(sA, 648, 0, CTX, mt);
    __syncthreads();
    mfin(mt, ut, sA, MP, WMC, MB);
  }
  gbar(ws, xcd, phase);
  {
    if (ut >= 16) stage512(sA, 520, 0, MB, mt);
    __syncthreads();
    if (ut >= 16) {
      f32x4 acc = {0.f, 0.f, 0.f, 0.f};
      acc = mm_part<4>(acc, sA, 520, 0, wv * 4, EMBB, 512, (ut - 16) * 16, lane);
      gx_write(gx, wv, lane, acc);
      __syncthreads();
      const int bl = tid >> 4, jl = tid & 15;
      st_coh_f32(LG + (size_t)(mt * 16 + bl) * NC + (ut - 16) * 16 + jl,
                 gx_sum(gx, bl, jl) + bproj[(ut - 16) * 16 + jl]);
    }
  }
  gbar(ws, xcd, phase);
  if (wg >= NB) lsm(wg - NB, NL - 1, LG, out, aux);
}

// ---------------- host entry ----------------
extern "C" void kernel_launch(void* const* d_in, const int* in_sizes, int n_in,
                              void* d_out, int out_size, void* d_ws, size_t ws_size,
                              hipStream_t stream) {
  (void)in_sizes; (void)n_in; (void)out_size;
  if (ws_size < OFF_END) return;

  const float* key   = (const float*)d_in[0];
  const float* value = (const float*)d_in[1];
  const int*   Yin   = (const int*)d_in[2];
  const int*   flens = (const int*)d_in[3];
  const float* emb   = (const float*)d_in[5];
  const float* Wq    = (const float*)d_in[6];
  const float* bq    = (const float*)d_in[7];
  const float* Wih1  = (const float*)d_in[8];
  const float* Whh1  = (const float*)d_in[9];
  const float* bih1  = (const float*)d_in[10];
  const float* bhh1  = (const float*)d_in[11];
  const float* Wih2  = (const float*)d_in[12];
  const float* Whh2  = (const float*)d_in[13];
  const float* bih2  = (const float*)d_in[14];
  const float* bhh2  = (const float*)d_in[15];
  const float* Wih3  = (const float*)d_in[16];
  const float* Whh3  = (const float*)d_in[17];
  const float* bih3  = (const float*)d_in[18];
  const float* bhh3  = (const float*)d_in[19];
  const float* Wmlp  = (const float*)d_in[20];
  const float* bmlp  = (const float*)d_in[21];
  const float* bproj = (const float*)d_in[22];
  const float* h00   = (const float*)d_in[23];
  const float* h01   = (const float*)d_in[24];
  const float* h02   = (const float*)d_in[25];
  const float* c00   = (const float*)d_in[26];
  const float* c01   = (const float*)d_in[27];
  const float* c02   = (const float*)d_in[28];
  float* out = (float*)d_out;
  char* ws = (char*)d_ws;

  dim3 cb(256);
#define CONV(src, off, r, c, ss, so) \
  k_conv<<<512, cb, 0, stream>>>(src, (u16*)(ws + off), r, c, ss, so)
  CONV(Whh1,  OFF_WHH1, 2048, 512, 512, 0);
  CONV(Wih1,  OFF_W1C,  2048, 128, 640, 512);
  CONV(Wih2,  OFF_WIH2, 2048, 512, 512, 0);
  CONV(Whh2,  OFF_WHH2, 2048, 512, 512, 0);
  CONV(Wih3,  OFF_WIH3, 2048, 512, 512, 0);
  CONV(Whh3,  OFF_WHH3, 2048, 512, 512, 0);
  CONV(Wmlp,  OFF_WMH,  512, 512, 640, 0);
  CONV(Wmlp,  OFF_WMC,  512, 128, 640, 512);
  CONV(Wq,    OFF_WQ,   128, 512, 512, 0);
  CONV(emb,   OFF_EMB,  256, 512, 512, 0);
  CONV(key,   OFF_KEY,  16384, 256, 256, 0);
  CONV(value, OFF_VAL,  32768, 128, 128, 0);
#undef CONV
  k_proj1<<<256, cb, 0, stream>>>(emb, Wih1, bih1, bhh1, (u16*)(ws + OFF_PROJ1));
  k_init<<<256, cb, 0, stream>>>(h00, h01, h02, c00, c01, c02,
                                 bih2, bhh2, bih3, bhh3, ws);
  k_dec<<<256, cb, 0, stream>>>(Yin, flens, bq, bmlp, bproj, out, ws);
}

// Round 4
// 16829.695 us; speedup vs baseline: 1.0080x; 1.0080x over previous
//
#include <hip/hip_runtime.h>

typedef unsigned short u16;
typedef unsigned int   u32;
typedef __bf16 bf16x8 __attribute__((ext_vector_type(8)));
typedef float  f32x4  __attribute__((ext_vector_type(4)));

#define NB 128   // batch
#define NH 512   // hidden
#define NA 128   // attention dim
#define NT 256   // encoder time
#define NC 256   // classes
#define NL 300   // decode steps
#define SA 1544  // LDS staging row stride (u16); 2*SA mod 128 == 16 -> free 2-way

// ---------------- workspace layout (bytes) ----------------
static constexpr size_t OFF_BAR   = 0;                         // 4 KiB barrier area (8 groups x 256B used)
static constexpr size_t OFF_H1    = 4096;                      // 2*128*512*2
static constexpr size_t OFF_H2    = OFF_H1   + 262144;
static constexpr size_t OFF_H3    = OFF_H2   + 262144;
static constexpr size_t OFF_C     = OFF_H3   + 262144;         // 3*128*512*4
static constexpr size_t OFF_CTX   = OFF_C    + 786432;         // 128*128*2
static constexpr size_t OFF_Q     = OFF_CTX  + 32768;          // (unused)
static constexpr size_t OFF_MP    = OFF_Q    + 65536;          // 128*512*4
static constexpr size_t OFF_M     = OFF_MP   + 262144;         // 128*512*2
static constexpr size_t OFF_LOG   = OFF_M    + 131072;         // 128*256*4
static constexpr size_t OFF_W1C   = OFF_LOG  + 131072;         // 2048*128*2
static constexpr size_t OFF_WHH1  = OFF_W1C  + 524288;         // 2048*512*2
static constexpr size_t OFF_WIH2  = OFF_WHH1 + 2097152;
static constexpr size_t OFF_WHH2  = OFF_WIH2 + 2097152;
static constexpr size_t OFF_WIH3  = OFF_WHH2 + 2097152;
static constexpr size_t OFF_WHH3  = OFF_WIH3 + 2097152;
static constexpr size_t OFF_WMH   = OFF_WHH3 + 2097152;        // 512*512*2
static constexpr size_t OFF_WMC   = OFF_WMH  + 524288;         // 512*128*2
static constexpr size_t OFF_WQ    = OFF_WMC  + 131072;         // 128*512*2
static constexpr size_t OFF_EMB   = OFF_WQ   + 131072;         // 256*512*2
static constexpr size_t OFF_PROJ1 = OFF_EMB  + 262144;         // 256*2048*2
static constexpr size_t OFF_BS2   = OFF_PROJ1+ 1048576;        // 2048*4
static constexpr size_t OFF_BS3   = OFF_BS2  + 8192;
static constexpr size_t OFF_KEY   = OFF_BS3  + 8192;           // KT [b][t][a] 8MB bf16
static constexpr size_t OFF_VAL   = OFF_KEY  + 8388608;        // VT [b][v][t] 8MB bf16
static constexpr size_t OFF_END   = OFF_VAL  + 8388608;

// ---------------- scalar helpers ----------------
__device__ __forceinline__ u16 f2bf(float f) {
  u32 u = __builtin_bit_cast(u32, f);
  u32 r = (u + 0x7FFFu + ((u >> 16) & 1u)) >> 16;
  return (u16)r;
}
__device__ __forceinline__ float bf2f(u16 h) {
  return __builtin_bit_cast(float, ((u32)h) << 16);
}
__device__ __forceinline__ float sigm(float x) { return 1.f / (1.f + __expf(-x)); }
__device__ __forceinline__ float ftanh(float x) {
  x = fminf(fmaxf(x, -15.f), 15.f);
  float e = __expf(2.f * x);
  return (e - 1.f) / (e + 1.f);
}

// ---------------- coherent (cross-XCD) access helpers ----------------
__device__ __forceinline__ float ld_coh_f32(const float* p) {
  float v;
  asm volatile("global_load_dword %0, %1, off sc0 sc1\n\ts_waitcnt vmcnt(0)"
               : "=v"(v) : "v"(p) : "memory");
  return v;
}
__device__ __forceinline__ u32 ld_coh_u32(const u32* p) {
  u32 v;
  asm volatile("global_load_dword %0, %1, off sc0 sc1\n\ts_waitcnt vmcnt(0)"
               : "=v"(v) : "v"(p) : "memory");
  return v;
}
__device__ __forceinline__ f32x4 ld_coh16(const u16* p) {
  f32x4 v;
  asm volatile("global_load_dwordx4 %0, %1, off sc0 sc1\n\ts_waitcnt vmcnt(0)"
               : "=v"(v) : "v"(p) : "memory");
  return v;
}
// issue-only variants: caller MUST vm_wait() before using outputs
__device__ __forceinline__ void ld4_issue(const u16* p, f32x4& a, f32x4& b, f32x4& c, f32x4& d) {
  asm volatile(
      "global_load_dwordx4 %0, %4, off sc0 sc1\n\t"
      "global_load_dwordx4 %1, %4, off offset:16 sc0 sc1\n\t"
      "global_load_dwordx4 %2, %4, off offset:32 sc0 sc1\n\t"
      "global_load_dwordx4 %3, %4, off offset:48 sc0 sc1"
      : "=&v"(a), "=&v"(b), "=&v"(c), "=&v"(d)
      : "v"(p) : "memory");
}
__device__ __forceinline__ void ld1_issue(const u16* p, f32x4& a) {
  asm volatile("global_load_dwordx4 %0, %1, off sc0 sc1" : "=&v"(a) : "v"(p) : "memory");
}
__device__ __forceinline__ void ldf_issue(const float* p, float& v) {
  asm volatile("global_load_dword %0, %1, off sc0 sc1" : "=&v"(v) : "v"(p) : "memory");
}
__device__ __forceinline__ void vm_wait() {
  asm volatile("s_waitcnt vmcnt(0)" ::: "memory");
}
__device__ __forceinline__ void st_coh_f32(float* p, float v) {
  asm volatile("global_store_dword %0, %1, off sc0 sc1" :: "v"(p), "v"(v) : "memory");
}
__device__ __forceinline__ void st_coh_bf16(u16* p, u16 v) {
  u32 vv = v;
  asm volatile("global_store_short %0, %1, off sc0 sc1" :: "v"(p), "v"(vv) : "memory");
}

// ---------------- per-group barrier (32 WGs, flat, monotonic) ----------------
__device__ __forceinline__ void gbar(char* ws, int grp, u32& phase) {
  asm volatile("s_waitcnt vmcnt(0)" ::: "memory");
  __syncthreads();
  if (threadIdx.x == 0) {
    u32* c = (u32*)(ws + OFF_BAR + 256 * (size_t)grp);
    ++phase;
    __hip_atomic_fetch_add(c, 1u, __ATOMIC_RELAXED, __HIP_MEMORY_SCOPE_AGENT);
    const u32 tgt = phase * 32u;
    while (ld_coh_u32(c) < tgt) { }
  }
  __syncthreads();
}

// ---------------- workgroup reductions ----------------
__device__ __forceinline__ float wgmax(float v, float* s) {
#pragma unroll
  for (int o = 32; o; o >>= 1) v = fmaxf(v, __shfl_xor(v, o, 64));
  if ((threadIdx.x & 63) == 0) s[threadIdx.x >> 6] = v;
  __syncthreads();
  v = fmaxf(fmaxf(s[0], s[1]), fmaxf(s[2], s[3]));
  __syncthreads();
  return v;
}
__device__ __forceinline__ float wgsum(float v, float* s) {
#pragma unroll
  for (int o = 32; o; o >>= 1) v += __shfl_xor(v, o, 64);
  if ((threadIdx.x & 63) == 0) s[threadIdx.x >> 6] = v;
  __syncthreads();
  v = s[0] + s[1] + s[2] + s[3];
  __syncthreads();
  return v;
}

// ---------------- LDS staging helpers (issue / write split) ----------------
__device__ __forceinline__ void stage512_issue(const u16* src, int mt, f32x4* r) {
  const int row = threadIdx.x >> 4, c4 = (threadIdx.x & 15) * 32;
  const u16* p = src + (((size_t)(mt * 16 + row)) << 9) + c4;
  ld4_issue(p, r[0], r[1], r[2], r[3]);
}
__device__ __forceinline__ void stage512_write(u16* sA, int lcol0, f32x4* r) {
  const int row = threadIdx.x >> 4, c4 = (threadIdx.x & 15) * 32;
  f32x4* dst = (f32x4*)(sA + (size_t)row * SA + lcol0 + c4);
  dst[0] = r[0]; dst[1] = r[1]; dst[2] = r[2]; dst[3] = r[3];
}

// ---------------- MFMA tile helper ----------------
template <int NKS>
__device__ __forceinline__ f32x4 mm_part(f32x4 acc, const u16* sAp, int lcol0,
                                         int ks0, const u16* W, int kw, int colbase, int lane) {
  const int ra = lane & 15, kg = lane >> 4;
  const u16* ap = sAp + (size_t)ra * SA + lcol0 + kg * 8 + ks0 * 32;
  const u16* wp = W + (size_t)(colbase + ra) * kw + kg * 8 + (size_t)ks0 * 32;
#pragma unroll
  for (int k = 0; k < NKS; ++k) {
    bf16x8 av = *(const bf16x8*)(ap + k * 32);
    bf16x8 bv = *(const bf16x8*)(wp + k * 32);
    acc = __builtin_amdgcn_mfma_f32_16x16x32_bf16(av, bv, acc, 0, 0, 0);
  }
  return acc;
}
__device__ __forceinline__ void gx_write(float (*gx)[16][17], int wv, int lane, f32x4 acc) {
  const int col = lane & 15, r0 = (lane >> 4) * 4;
#pragma unroll
  for (int r = 0; r < 4; ++r) gx[wv][r0 + r][col] = acc[r];
}
__device__ __forceinline__ float gx_sum(float (*gx)[16][17], int bl, int jl) {
  return gx[0][bl][jl] + gx[1][bl][jl] + gx[2][bl][jl] + gx[3][bl][jl];
}

// ---------------- LSTM cell epilogue ----------------
__device__ __forceinline__ void cell_update(int layer, int mt, int ut, int t,
                                            float (*gx)[16][17], const int* Yin,
                                            const u16* proj1, const float* bsum,
                                            float* CB, u16* hout) {
  const int bl = threadIdx.x >> 4, ul = threadIdx.x & 15;
  const int bg = mt * 16 + bl, ug = ut * 16 + ul;
  float iv = gx[0][bl][ul], fv = gx[1][bl][ul], gv = gx[2][bl][ul], ov = gx[3][bl][ul];
  if (proj1) {
    const int y = Yin[bg * NL + t];
    const u16* pr = proj1 + (size_t)y * 2048 + ug;
    iv += bf2f(pr[0]); fv += bf2f(pr[512]); gv += bf2f(pr[1024]); ov += bf2f(pr[1536]);
  } else {
    iv += bsum[ug]; fv += bsum[512 + ug]; gv += bsum[1024 + ug]; ov += bsum[1536 + ug];
  }
  float* cp = CB + ((size_t)layer * NB + bg) * NH + ug;
  const float c0 = *cp;
  const float ii = sigm(iv), ff = sigm(fv), gg = ftanh(gv), oo = sigm(ov);
  const float cn = ff * c0 + ii * gg;
  *cp = cn;
  st_coh_bf16(hout + (size_t)bg * NH + ug, f2bf(oo * ftanh(cn)));
}

// ---------------- attention (q + energy + softmax + ctx), one WG per batch ----------------
__device__ void attn2(int b, const u16* h3row, const int* flens, const u16* WQ,
                      const u16* KT, const u16* VT, u16* CTX, const float* bq,
                      u16* hq, float* aux) {
  const int tid = threadIdx.x;
  if (tid < 64) {                         // stage h3[b][:] (1 KB, coherent)
    f32x4 v = ld_coh16(h3row + tid * 8);
    *(f32x4*)(hq + tid * 8) = v;
  }
  __syncthreads();
  if (tid < NA) {                         // q[j] = h3 . Wq[j] + bq[j]
    const bf16x8* wr = (const bf16x8*)(WQ + (size_t)tid * NH);
    float qv = bq[tid];
#pragma unroll 8
    for (int k8 = 0; k8 < 64; ++k8) {
      bf16x8 w8 = wr[k8];
#pragma unroll
      for (int kk = 0; kk < 8; ++kk) qv += bf2f(hq[k8 * 8 + kk]) * (float)w8[kk];
    }
    aux[tid] = qv;
  }
  __syncthreads();
  const int fl = flens[b] >> 3;           // frame_lens // 8 (128..256)
  float e = -3.0e38f;
  {
    const bf16x8* kr = (const bf16x8*)(KT + ((size_t)b * NT + tid) * NA);
    float s = 0.f;
#pragma unroll
    for (int k8 = 0; k8 < 16; ++k8) {
      bf16x8 kv = __builtin_nontemporal_load(kr + k8);
#pragma unroll
      for (int kk = 0; kk < 8; ++kk) s += aux[k8 * 8 + kk] * (float)kv[kk];
    }
    if (tid < fl) e = s;
  }
  const float mx = wgmax(e, aux + 400);
  float ex = (tid < fl) ? __expf(e - mx) : 0.f;
  const float sm = wgsum(ex, aux + 400);
  aux[128 + tid] = ex / sm;
  __syncthreads();
  if (tid < NA) {                         // ctx[v] = p . VT[b][v][:]
    const bf16x8* vr = (const bf16x8*)(VT + ((size_t)b * NA + tid) * NT);
    float c = 0.f;
#pragma unroll
    for (int k8 = 0; k8 < 32; ++k8) {
      bf16x8 vv = __builtin_nontemporal_load(vr + k8);
#pragma unroll
      for (int kk = 0; kk < 8; ++kk) c += aux[128 + k8 * 8 + kk] * (float)vv[kk];
    }
    st_coh_bf16(CTX + (size_t)b * NA + tid, f2bf(c));
  }
}

__device__ void lsm(int b, int tp, const float* LG, float* out, float* aux) {
  const int tid = threadIdx.x;
  const float l = ld_coh_f32(LG + (size_t)b * NC + tid);
  const float mx = wgmax(l, aux + 400);
  const float ex = __expf(l - mx);
  const float sm = wgsum(ex, aux + 400);
  out[((size_t)b * NL + tp) * NC + tid] = l - mx - __logf(sm);
}

// ---------------- prep kernels ----------------
__global__ void k_conv(const float* __restrict__ src, u16* __restrict__ dst,
                       int rows, int cols, int sstride, int soff) {
  const int n = rows * cols;
  for (int i = blockIdx.x * blockDim.x + threadIdx.x; i < n; i += gridDim.x * blockDim.x) {
    const int r = i / cols, c = i - r * cols;
    dst[i] = f2bf(src[(size_t)r * sstride + soff + c]);
  }
}

// batched transpose + f32->bf16: src [B][R][C] f32 -> dst [B][C][R] bf16
__global__ void k_trans(const float* __restrict__ src, u16* __restrict__ dst, int R, int C) {
  __shared__ float tile[32][33];
  const int rt = R >> 5, ct = C >> 5;
  const int bid = blockIdx.x;
  const int b = bid / (rt * ct), rem = bid % (rt * ct);
  const int r0 = (rem / ct) * 32, c0 = (rem % ct) * 32;
  const int tr = threadIdx.x >> 5, tc = threadIdx.x & 31;
  const float* s = src + ((size_t)b * R + r0) * C + c0;
#pragma unroll
  for (int i = 0; i < 4; ++i) tile[tr + i * 8][tc] = s[(size_t)(tr + i * 8) * C + tc];
  __syncthreads();
  u16* d = dst + ((size_t)b * C + c0) * R + r0;
#pragma unroll
  for (int i = 0; i < 4; ++i) d[(size_t)(tr + i * 8) * R + tc] = f2bf(tile[tc][tr + i * 8]);
}

__global__ void k_proj1(const float* __restrict__ emb, const float* __restrict__ Wih1,
                        const float* __restrict__ bih1, const float* __restrict__ bhh1,
                        u16* __restrict__ proj) {
  __shared__ float se[8][512];
  const int c0 = (blockIdx.x >> 3) * 8;
  const int g = (blockIdx.x & 7) * 256 + threadIdx.x;
  for (int i = threadIdx.x; i < 4096; i += 256)
    se[i >> 9][i & 511] = emb[(size_t)(c0 + (i >> 9)) * NH + (i & 511)];
  __syncthreads();
  const float bb = bih1[g] + bhh1[g];
  const float* w = Wih1 + (size_t)g * 640;
  for (int cc = 0; cc < 8; ++cc) {
    float s = 0.f;
#pragma unroll 8
    for (int k = 0; k < 512; ++k) s += se[cc][k] * w[k];
    proj[(size_t)(c0 + cc) * 2048 + g] = f2bf(s + bb);
  }
}

__global__ void k_init(const float* h00, const float* h01, const float* h02,
                       const float* c00, const float* c01, const float* c02,
                       const float* bih2, const float* bhh2,
                       const float* bih3, const float* bhh3, char* ws) {
  const int i = blockIdx.x * 256 + threadIdx.x;
  u16* H1 = (u16*)(ws + OFF_H1);
  u16* H2 = (u16*)(ws + OFF_H2);
  u16* H3 = (u16*)(ws + OFF_H3);
  float* CB = (float*)(ws + OFF_C);
  const int k = i & 511;
  H1[i] = f2bf(h00[k]); H2[i] = f2bf(h01[k]); H3[i] = f2bf(h02[k]);
  CB[i] = c00[k]; CB[65536 + i] = c01[k]; CB[131072 + i] = c02[k];
  if (i < 2048) {
    ((float*)(ws + OFF_BS2))[i] = bih2[i] + bhh2[i];
    ((float*)(ws + OFF_BS3))[i] = bih3[i] + bhh3[i];
  }
  if (i < 1024) ((u32*)(ws + OFF_BAR))[i] = 0;
}

// ---------------- the persistent decoder ----------------
__global__ void __launch_bounds__(256, 1) k_dec(
    const int* __restrict__ Yin, const int* __restrict__ flens,
    const float* __restrict__ bq, const float* __restrict__ bmlp,
    const float* __restrict__ bproj, float* __restrict__ out, char* __restrict__ ws) {
  __shared__ __align__(16) u16 sA[16 * SA];     // 49,408 B staging
  __shared__ float gx[4][16][17];               // cross-wave exchange
  __shared__ float aux[416];
  __shared__ __align__(16) u16 hq[512];

  u16* H1 = (u16*)(ws + OFF_H1);
  u16* H2 = (u16*)(ws + OFF_H2);
  u16* H3 = (u16*)(ws + OFF_H3);
  float* CB = (float*)(ws + OFF_C);
  u16* CTX = (u16*)(ws + OFF_CTX);
  float* MP = (float*)(ws + OFF_MP);
  u16* MB = (u16*)(ws + OFF_M);
  float* LG = (float*)(ws + OFF_LOG);
  const u16* W1C  = (const u16*)(ws + OFF_W1C);
  const u16* WHH1 = (const u16*)(ws + OFF_WHH1);
  const u16* WIH2 = (const u16*)(ws + OFF_WIH2);
  const u16* WHH2 = (const u16*)(ws + OFF_WHH2);
  const u16* WIH3 = (const u16*)(ws + OFF_WIH3);
  const u16* WHH3 = (const u16*)(ws + OFF_WHH3);
  const u16* WMH  = (const u16*)(ws + OFF_WMH);
  const u16* WMC  = (const u16*)(ws + OFF_WMC);
  const u16* WQB  = (const u16*)(ws + OFF_WQ);
  const u16* EMBB = (const u16*)(ws + OFF_EMB);
  const u16* PJ1  = (const u16*)(ws + OFF_PROJ1);
  const float* BS2 = (const float*)(ws + OFF_BS2);
  const float* BS3 = (const float*)(ws + OFF_BS3);
  const u16* KT = (const u16*)(ws + OFF_KEY);
  const u16* VT = (const u16*)(ws + OFF_VAL);

  const int wg = blockIdx.x, tid = threadIdx.x;
  const int lane = tid & 63, wv = tid >> 6;
  const int mt = wg >> 5;          // group = batch tile (8 groups x 32 WGs)
  const int ut = wg & 31;          // gate/unit tile within group
  const int bl = tid >> 4, jl = tid & 15;
  u32 phase = 0;

  // ======== pre-loop: ctx(init) from initial h3 ========
  if (ut >= 16)
    attn2(mt * 16 + (ut - 16), H3 + (size_t)(mt * 16 + (ut - 16)) * NH,
          flens, WQB, KT, VT, CTX, bq, hq, aux);
  gbar(ws, mt, phase);

  // ======== main loop: 4 phases/step ========
  for (int t = 0; t < NL; ++t) {
    const int o = t & 1, n = o ^ 1;
    u16* h1o = H1 + o * 65536; u16* h1n = H1 + n * 65536;
    u16* h2o = H2 + o * 65536; u16* h2n = H2 + n * 65536;
    u16* h3o = H3 + o * 65536; u16* h3n = H3 + n * 65536;

    // ---- phase A: LSTM1 + m-finish(t-1)
    {
      f32x4 rc, rh[4]; float mpv = 0.f;
      { const int row = tid >> 4, c1 = (tid & 15) * 8;
        ld1_issue(CTX + (size_t)(mt * 16 + row) * NA + c1, rc); }
      stage512_issue(h1o, mt, rh);
      if (t >= 1) ldf_issue(MP + (size_t)(mt * 16 + bl) * NH + ut * 16 + jl, mpv);
      vm_wait();
      { const int row = tid >> 4, c1 = (tid & 15) * 8;
        *(f32x4*)(sA + (size_t)row * SA + c1) = rc; }
      stage512_write(sA, 128, rh);
      __syncthreads();
      f32x4 acc = {0.f, 0.f, 0.f, 0.f};
      const int colbase = wv * 512 + ut * 16;
      acc = mm_part<4>(acc, sA, 0, 0, W1C, 128, colbase, lane);
      acc = mm_part<16>(acc, sA, 128, 0, WHH1, 512, colbase, lane);
      gx_write(gx, wv, lane, acc);
      __syncthreads();
      cell_update(0, mt, ut, t, gx, Yin, PJ1, nullptr, CB, h1n);
      __syncthreads();
      if (t >= 1) {
        f32x4 a2 = {0.f, 0.f, 0.f, 0.f};
        a2 = mm_part<1>(a2, sA, 0, wv, WMC, 128, ut * 16, lane);
        gx_write(gx, wv, lane, a2);
      }
      __syncthreads();
      if (t >= 1) {
        float s = gx_sum(gx, bl, jl) + mpv;
        s = (s >= 0.f) ? s : 0.01f * s;
        st_coh_bf16(MB + (size_t)(mt * 16 + bl) * NH + ut * 16 + jl, f2bf(s));
      }
    }
    gbar(ws, mt, phase);

    // ---- phase B: LSTM2 + proj(t-1) on uts 16..31
    {
      f32x4 r1[4], r2[4], r3[4];
      stage512_issue(h1n, mt, r1);
      stage512_issue(h2o, mt, r2);
      const bool dop = (ut >= 16) && (t >= 1);
      if (dop) stage512_issue(MB, mt, r3);
      vm_wait();
      stage512_write(sA, 0, r1);
      stage512_write(sA, 512, r2);
      if (dop) stage512_write(sA, 1024, r3);
      __syncthreads();
      f32x4 acc = {0.f, 0.f, 0.f, 0.f};
      const int colbase = wv * 512 + ut * 16;
      acc = mm_part<16>(acc, sA, 0, 0, WIH2, 512, colbase, lane);
      acc = mm_part<16>(acc, sA, 512, 0, WHH2, 512, colbase, lane);
      gx_write(gx, wv, lane, acc);
      __syncthreads();
      cell_update(1, mt, ut, t, gx, Yin, nullptr, BS2, CB, h2n);
      __syncthreads();
      if (dop) {
        f32x4 a2 = {0.f, 0.f, 0.f, 0.f};
        a2 = mm_part<4>(a2, sA, 1024, wv * 4, EMBB, 512, (ut - 16) * 16, lane);
        gx_write(gx, wv, lane, a2);
      }
      __syncthreads();
      if (dop)
        st_coh_f32(LG + (size_t)(mt * 16 + bl) * NC + (ut - 16) * 16 + jl,
                   gx_sum(gx, bl, jl) + bproj[(ut - 16) * 16 + jl]);
    }
    gbar(ws, mt, phase);

    // ---- phase C: LSTM3 + log-softmax(t-1) on uts 0..15
    {
      f32x4 r1[4], r2[4];
      stage512_issue(h2n, mt, r1);
      stage512_issue(h3o, mt, r2);
      vm_wait();
      stage512_write(sA, 0, r1);
      stage512_write(sA, 512, r2);
      __syncthreads();
      f32x4 acc = {0.f, 0.f, 0.f, 0.f};
      const int colbase = wv * 512 + ut * 16;
      acc = mm_part<16>(acc, sA, 0, 0, WIH3, 512, colbase, lane);
      acc = mm_part<16>(acc, sA, 512, 0, WHH3, 512, colbase, lane);
      gx_write(gx, wv, lane, acc);
      __syncthreads();
      cell_update(2, mt, ut, t, gx, Yin, nullptr, BS3, CB, h3n);
      if (ut < 16 && t >= 1) lsm(mt * 16 + ut, t - 1, LG, out, aux);
    }
    gbar(ws, mt, phase);

    // ---- phase E: attention(t) on uts 16..31  ||  m_partial(t) on uts 0..15
    {
      if (ut < 16) {
        f32x4 rh[4];
        stage512_issue(h3n, mt, rh);
        vm_wait();
        stage512_write(sA, 0, rh);
        __syncthreads();
#pragma unroll
        for (int half = 0; half < 2; ++half) {
          const int cb = ut * 32 + half * 16;
          f32x4 acc = {0.f, 0.f, 0.f, 0.f};
          acc = mm_part<4>(acc, sA, 0, wv * 4, WMH, 512, cb, lane);
          gx_write(gx, wv, lane, acc);
          __syncthreads();
          st_coh_f32(MP + (size_t)(mt * 16 + bl) * NH + cb + jl,
                     gx_sum(gx, bl, jl) + bmlp[cb + jl]);
          __syncthreads();
        }
      } else {
        const int b = mt * 16 + (ut - 16);
        attn2(b, h3n + (size_t)b * NH, flens, WQB, KT, VT, CTX, bq, hq, aux);
      }
    }
    gbar(ws, mt, phase);
  }

  // ======== tail: finish head of t = 299 ========
  {  // T1: m-finish
    f32x4 rc; float mpv = 0.f;
    { const int row = tid >> 4, c1 = (tid & 15) * 8;
      ld1_issue(CTX + (size_t)(mt * 16 + row) * NA + c1, rc); }
    ldf_issue(MP + (size_t)(mt * 16 + bl) * NH + ut * 16 + jl, mpv);
    vm_wait();
    { const int row = tid >> 4, c1 = (tid & 15) * 8;
      *(f32x4*)(sA + (size_t)row * SA + c1) = rc; }
    __syncthreads();
    f32x4 a2 = {0.f, 0.f, 0.f, 0.f};
    a2 = mm_part<1>(a2, sA, 0, wv, WMC, 128, ut * 16, lane);
    gx_write(gx, wv, lane, a2);
    __syncthreads();
    float s = gx_sum(gx, bl, jl) + mpv;
    s = (s >= 0.f) ? s : 0.01f * s;
    st_coh_bf16(MB + (size_t)(mt * 16 + bl) * NH + ut * 16 + jl, f2bf(s));
  }
  gbar(ws, mt, phase);
  {  // T2: tied projection
    if (ut >= 16) {
      f32x4 r3[4];
      stage512_issue(MB, mt, r3);
      vm_wait();
      stage512_write(sA, 0, r3);
      __syncthreads();
      f32x4 a2 = {0.f, 0.f, 0.f, 0.f};
      a2 = mm_part<4>(a2, sA, 0, wv * 4, EMBB, 512, (ut - 16) * 16, lane);
      gx_write(gx, wv, lane, a2);
      __syncthreads();
      st_coh_f32(LG + (size_t)(mt * 16 + bl) * NC + (ut - 16) * 16 + jl,
                 gx_sum(gx, bl, jl) + bproj[(ut - 16) * 16 + jl]);
    }
  }
  gbar(ws, mt, phase);
  // T3: final log-softmax
  if (ut < 16) lsm(mt * 16 + ut, NL - 1, LG, out, aux);
}

// ---------------- host entry ----------------
extern "C" void kernel_launch(void* const* d_in, const int* in_sizes, int n_in,
                              void* d_out, int out_size, void* d_ws, size_t ws_size,
                              hipStream_t stream) {
  (void)in_sizes; (void)n_in; (void)out_size;
  if (ws_size < OFF_END) return;

  const float* key   = (const float*)d_in[0];
  const float* value = (const float*)d_in[1];
  const int*   Yin   = (const int*)d_in[2];
  const int*   flens = (const int*)d_in[3];
  const float* emb   = (const float*)d_in[5];
  const float* Wq    = (const float*)d_in[6];
  const float* bq    = (const float*)d_in[7];
  const float* Wih1  = (const float*)d_in[8];
  const float* Whh1  = (const float*)d_in[9];
  const float* bih1  = (const float*)d_in[10];
  const float* bhh1  = (const float*)d_in[11];
  const float* Wih2  = (const float*)d_in[12];
  const float* Whh2  = (const float*)d_in[13];
  const float* bih2  = (const float*)d_in[14];
  const float* bhh2  = (const float*)d_in[15];
  const float* Wih3  = (const float*)d_in[16];
  const float* Whh3  = (const float*)d_in[17];
  const float* bih3  = (const float*)d_in[18];
  const float* bhh3  = (const float*)d_in[19];
  const float* Wmlp  = (const float*)d_in[20];
  const float* bmlp  = (const float*)d_in[21];
  const float* bproj = (const float*)d_in[22];
  const float* h00   = (const float*)d_in[23];
  const float* h01   = (const float*)d_in[24];
  const float* h02   = (const float*)d_in[25];
  const float* c00   = (const float*)d_in[26];
  const float* c01   = (const float*)d_in[27];
  const float* c02   = (const float*)d_in[28];
  float* out = (float*)d_out;
  char* ws = (char*)d_ws;

  dim3 cb(256);
#define CONV(src, off, r, c, ss, so) \
  k_conv<<<512, cb, 0, stream>>>(src, (u16*)(ws + off), r, c, ss, so)
  CONV(Whh1,  OFF_WHH1, 2048, 512, 512, 0);
  CONV(Wih1,  OFF_W1C,  2048, 128, 640, 512);
  CONV(Wih2,  OFF_WIH2, 2048, 512, 512, 0);
  CONV(Whh2,  OFF_WHH2, 2048, 512, 512, 0);
  CONV(Wih3,  OFF_WIH3, 2048, 512, 512, 0);
  CONV(Whh3,  OFF_WHH3, 2048, 512, 512, 0);
  CONV(Wmlp,  OFF_WMH,  512, 512, 640, 0);
  CONV(Wmlp,  OFF_WMC,  512, 128, 640, 512);
  CONV(Wq,    OFF_WQ,   128, 512, 512, 0);
  CONV(emb,   OFF_EMB,  256, 512, 512, 0);
#undef CONV
  k_trans<<<4096, cb, 0, stream>>>(key,   (u16*)(ws + OFF_KEY), 128, 256);  // KT[b][t][a]
  k_trans<<<4096, cb, 0, stream>>>(value, (u16*)(ws + OFF_VAL), 256, 128);  // VT[b][v][t]
  k_proj1<<<256, cb, 0, stream>>>(emb, Wih1, bih1, bhh1, (u16*)(ws + OFF_PROJ1));
  k_init<<<256, cb, 0, stream>>>(h00, h01, h02, c00, c01, c02,
                                 bih2, bhh2, bih3, bhh3, ws);
  k_dec<<<256, cb, 0, stream>>>(Yin, flens, bq, bmlp, bproj, out, ws);
}